// Round 4
// baseline (1223.340 us; speedup 1.0000x reference)
//
#include <hip/hip_runtime.h>

// GeometryTransformation: backproject(theta=0) -> 2x resblock(conv3d 16->16 3^3,
// InstanceNorm, ReLU, residual) -> forward-project at theta in {0, pi/2}.
//
// Round-4: conv restructured for B-fragment reuse. K = kx{0,1 | 2,pad} x 16ci,
// so one halo-row read (2 x ds_read_b128) feeds up to 6 MFMAs into 8 per-wave
// y-accumulators (2.4x LDS-read reuse). Tile 4z x 8y x 16x (40KB LDS -> 3-4
// blocks/CU vs 2 before). InstanceNorm stats fused into conv epilogue
// (shfl + LDS-combined atomics) - reduce_k deleted.
//
// Verified identities (round-2/3 kernels passed with these):
//   backproject: vol0[c,d,y,x] = proj[c,0,d,y]
//   fproj 0:     out[c,0,d,i] = sum_x vol2[c,d,i,x]
//   fproj pi/2:  out[c,1,d,i] = sum_y vol2[c,d,y,i], EXCEPT i==0 sums y<64 only.

typedef unsigned short u16;
typedef unsigned int   u32;
using s16x8 = __attribute__((ext_vector_type(8))) short;
using f32x4 = __attribute__((ext_vector_type(4))) float;

#define NV        (1 << 21)
#define VOL_ELEMS (16 * NV)
#define WS_NEED   (3ull * VOL_ELEMS * 2ull + 4096ull)

__device__ __forceinline__ float bf2f(u16 h) {
    union { u32 u; float f; } v; v.u = ((u32)h) << 16; return v.f;
}
__device__ __forceinline__ u16 f2bf(float f) {
    union { float f; u32 u; } v; v.f = f;
    u32 u = v.u;
    return (u16)((u + 0x7fffu + ((u >> 16) & 1u)) >> 16);
}
__device__ __forceinline__ float ldin(const void* p, int i, int bf) {
    return bf ? bf2f(((const u16*)p)[i]) : ((const float*)p)[i];
}
__device__ __forceinline__ u16 ldbf(const void* p, int i, int bf) {
    return bf ? ((const u16*)p)[i] : f2bf(((const float*)p)[i]);
}
__device__ __forceinline__ void unpack8(uint4 a, float* f) {
    u32 w[4] = {a.x, a.y, a.z, a.w};
#pragma unroll
    for (int i = 0; i < 4; i++) {
        f[2*i]   = bf2f((u16)(w[i] & 0xffff));
        f[2*i+1] = bf2f((u16)(w[i] >> 16));
    }
}
__device__ __forceinline__ void unpack16(uint4 a, uint4 b, float* f) {
    unpack8(a, f);
    unpack8(b, f + 8);
}

// stats zero + dtype sniff (bf16 vs fp32) from w_a1 bit patterns.
__global__ void init_k(const void* __restrict__ w, float* __restrict__ st,
                       int* __restrict__ flag)
{
    const int tid = threadIdx.x;
    for (int i = tid; i < 256; i += 64) st[i] = 0.f;
    if (tid == 0) {
        const u16* p = (const u16*)w;
        int cnt = 0;
        for (int i = 0; i < 32; i++) {
            int e = (p[2 * i] >> 7) & 0xFF;
            if (e >= 64 && e <= 130) cnt++;
        }
        *flag = (cnt >= 24) ? 1 : 0;
    }
}

__global__ void sentinel_k(u16* __restrict__ out, int n)
{
    int i = blockIdx.x * 256 + threadIdx.x;
    if (i < n) out[i] = 0x4640;
}

// ---------------------------------------------------------------------------
// MFMA conv, fused stats. Block tile: 4z x 8y x 16x outputs, 256 thr / 4 waves,
// wave w owns z-slice d0+w with 8 y-accumulators (f32x4 each).
// Halo 6z x 10y x 19x voxels in LDS as uint4 tile[z][y][half][x] (19 units/row;
// x index 18 is the kx-pad column - always staged, so finite).
// K-packing: k = kx*16 + ci; frag0 = kx{0,1}, frag1 = kx{2,pad(zero A)}.
// Lane l: n=l&15 (co / out-x), g=l>>4, h=g&1 (ci half), kxs=g>>1 (kx parity).
// B-frag addr (16B units) = row + h*19 + n + kxs (+2 for frag1) -> ds_read_b128.
// MODE 0: in = proj bcast | 1: relu((t-m)s) | 2: relu((t-m)s + proj bcast)
// ---------------------------------------------------------------------------
template <int MODE>
__global__ __launch_bounds__(256) void conv_k(
    const u16*  __restrict__ t,      // prev conv raw out, [d][y][x][c] bf16
    const void* __restrict__ proj,   // projection input (flag dtype)
    const float* __restrict__ st_in, // prev stats: m at +32, s at +48
    const void* __restrict__ wgt,    // (co,ci,3,3,3)
    const void* __restrict__ bias,   // (16,)
    const int*  __restrict__ flagp,
    u16* __restrict__ out,           // raw conv+bias out, [d][y][x][c] bf16
    float* __restrict__ st_out)      // this conv's stat block (sums at 0/16)
{
    __shared__ uint4 tile[2280];     // 36.48 KB  [z6][y10][h2][x19]
    __shared__ float prv[960];       //  3.84 KB  [z6][y10][ci16]
    __shared__ float sred[32];
    const int bf  = *flagp;
    const int tid = threadIdx.x;
    const int l   = tid & 63;
    const int w   = tid >> 6;
    const int n   = l & 15;
    const int g   = l >> 4;
    const int h   = g & 1;
    const int kxs = g >> 1;

    const int x0 = blockIdx.x * 16;
    const int y0 = blockIdx.y * 8;
    const int d0 = blockIdx.z * 4;

    if (tid < 32) sred[tid] = 0.f;

    float mm[16], ss[16];
    if (MODE != 0) {
#pragma unroll
        for (int ci = 0; ci < 16; ci++) { mm[ci] = st_in[32 + ci]; ss[ci] = st_in[48 + ci]; }
    }

    if (MODE != 1) {
        for (int i = tid; i < 960; i += 256) {
            int z = i / 160, rr = i - z * 160;
            int y = rr >> 4, ci = rr & 15;
            int gz = d0 + z - 1, gy = y0 + y - 1;
            float v = 0.f;
            if ((unsigned)gz < 128u && (unsigned)gy < 128u)
                v = ldin(proj, (ci << 14) + (gz << 7) + gy, bf);
            prv[i] = v;
        }
        __syncthreads();
    }

    // stage halo: 2280 half-voxels (8ch = 16B each)
    for (int u = tid; u < 2280; u += 256) {
        int z  = u / 380, r1 = u - z * 380;
        int y  = r1 / 38, r2 = r1 - y * 38;
        int hh = r2 / 19, x  = r2 - hh * 19;
        int gz = d0 + z - 1, gy = y0 + y - 1, gx = x0 + x - 1;
        bool vin = (unsigned)gz < 128u && (unsigned)gy < 128u && (unsigned)gx < 128u;
        float val[8];
        if (MODE == 0) {
#pragma unroll
            for (int j = 0; j < 8; j++)
                val[j] = vin ? prv[(z * 10 + y) * 16 + hh * 8 + j] : 0.f;
        } else {
            if (vin) {
                uint4 raw = *(const uint4*)(t + (((((gz << 7) + gy) << 7) + gx) << 4) + hh * 8);
                float f[8];
                unpack8(raw, f);
#pragma unroll
                for (int j = 0; j < 8; j++) {
                    float m = hh ? mm[8 + j] : mm[j];
                    float s = hh ? ss[8 + j] : ss[j];
                    float pv = (MODE == 2) ? prv[(z * 10 + y) * 16 + hh * 8 + j] : 0.f;
                    val[j] = fmaxf((f[j] - m) * s + pv, 0.f);
                }
            } else {
#pragma unroll
                for (int j = 0; j < 8; j++) val[j] = 0.f;
            }
        }
        u32 pw[4];
#pragma unroll
        for (int j = 0; j < 4; j++)
            pw[j] = (u32)f2bf(val[2*j]) | ((u32)f2bf(val[2*j+1]) << 16);
        tile[u] = make_uint4(pw[0], pw[1], pw[2], pw[3]);
    }

    // A-fragments (loaded after staging to cap peak VGPR pressure)
    s16x8 af[3][3][2];
#pragma unroll
    for (int kz = 0; kz < 3; kz++)
#pragma unroll
        for (int ky = 0; ky < 3; ky++)
#pragma unroll
            for (int grp = 0; grp < 2; grp++) {
                int kx = grp * 2 + kxs;     // 0,1 | 2,3(pad)
                s16x8 a;
#pragma unroll
                for (int e = 0; e < 8; e++) {
                    int ci = h * 8 + e;
                    u16 wv = 0;
                    if (kx <= 2)
                        wv = ldbf(wgt, n * 432 + ci * 27 + kz * 9 + ky * 3 + kx, bf);
                    a[e] = (short)wv;
                }
                af[kz][ky][grp] = a;
            }

    f32x4 binit;
#pragma unroll
    for (int r = 0; r < 4; r++) binit[r] = ldin(bias, g * 4 + r, bf);

    __syncthreads();

    // compute: wave w -> z-slice d0+w; 30 halo rows -> 60 reads -> 144 MFMAs
    f32x4 acc[8];
#pragma unroll
    for (int yl = 0; yl < 8; yl++) acc[yl] = binit;

    const int labase = h * 19 + n + kxs;
#pragma unroll
    for (int kz = 0; kz < 3; kz++) {
        const int zt = w + kz;
#pragma unroll
        for (int yin = 0; yin < 10; yin++) {
            const int R = (zt * 10 + yin) * 38 + labase;
            s16x8 f0 = __builtin_bit_cast(s16x8, tile[R]);
            s16x8 f1 = __builtin_bit_cast(s16x8, tile[R + 2]);
#pragma unroll
            for (int ky = 0; ky < 3; ky++) {
                const int yl = yin - ky;            // out row y0+yl reads in row yl+ky
                if (yl >= 0 && yl < 8) {
                    acc[yl] = __builtin_amdgcn_mfma_f32_16x16x32_bf16(af[kz][ky][0], f0, acc[yl], 0, 0, 0);
                    acc[yl] = __builtin_amdgcn_mfma_f32_16x16x32_bf16(af[kz][ky][1], f1, acc[yl], 0, 0, 0);
                }
            }
        }
    }

    // epilogue: store (D: col=lane&15 -> x, row=g*4+r -> co) + fused stats
    float sr[4] = {0.f, 0.f, 0.f, 0.f}, qr[4] = {0.f, 0.f, 0.f, 0.f};
    const int gz = d0 + w;
#pragma unroll
    for (int yl = 0; yl < 8; yl++) {
        const int gy = y0 + yl;
        u32 lo = (u32)f2bf(acc[yl][0]) | ((u32)f2bf(acc[yl][1]) << 16);
        u32 hi = (u32)f2bf(acc[yl][2]) | ((u32)f2bf(acc[yl][3]) << 16);
        *(uint2*)(out + (((((gz << 7) + gy) << 7) + (x0 + n)) << 4) + g * 4) =
            make_uint2(lo, hi);
#pragma unroll
        for (int r = 0; r < 4; r++) {
            sr[r] += acc[yl][r];
            qr[r] = fmaf(acc[yl][r], acc[yl][r], qr[r]);
        }
    }
#pragma unroll
    for (int off = 1; off < 16; off <<= 1) {
#pragma unroll
        for (int r = 0; r < 4; r++) {
            sr[r] += __shfl_down(sr[r], off, 16);
            qr[r] += __shfl_down(qr[r], off, 16);
        }
    }
    if (n == 0) {
#pragma unroll
        for (int r = 0; r < 4; r++) {
            atomicAdd(&sred[g * 4 + r], sr[r]);
            atomicAdd(&sred[16 + g * 4 + r], qr[r]);
        }
    }
    __syncthreads();
    if (tid < 32) atomicAdd(&st_out[tid], sred[tid]);
}

__global__ void finalize_k(float* st)
{
    const int c = threadIdx.x;
    if (c < 16) {
        const float inv = 1.f / 2097152.f;
        float m = st[c] * inv;
        float v = st[16 + c] * inv - m * m;
        st[32 + c] = m;
        st[48 + c] = rsqrtf(v + 1e-5f);
    }
}

// fproj: block per d. vol2 = relu((y4-m3)s3 + relu((y2-m1)s1 + proj)).
// Strips of 8 y-rows staged fp32 in LDS; rows reduced via shfl, cols via
// per-thread register accumulators. x==0 col sums y<64 only (fp32 quirk).
__global__ __launch_bounds__(256) void fproj_k(
    const u16* __restrict__ y2, const u16* __restrict__ y4,
    const void* __restrict__ proj, const float* __restrict__ st,
    const int* __restrict__ flagp, void* __restrict__ out)
{
    __shared__ float prw[128 * 16];
    __shared__ float sbuf[8 * 128 * 16];
    __shared__ float sA[64];
    const int bf = *flagp;
    const int d = blockIdx.x;
    const int tid = threadIdx.x;
    for (int i = tid; i < 2048; i += 256) {
        int y = i >> 4, ci = i & 15;
        prw[i] = ldin(proj, ci * 16384 + d * 128 + y, bf);
    }
    if (tid < 16)      sA[tid] = st[64 + 32 + tid];
    else if (tid < 32) sA[tid] = st[64 + 48 + (tid - 16)];
    else if (tid < 48) sA[tid] = st[192 + 32 + (tid - 32)];
    else if (tid < 64) sA[tid] = st[192 + 48 + (tid - 48)];
    __syncthreads();

    const int y_loc = tid >> 5, xg = tid & 31;
    const int xB = tid >> 1, chalf = tid & 1;
    float colr[8], colr0[8];
#pragma unroll
    for (int j = 0; j < 8; j++) { colr[j] = 0.f; colr0[j] = 0.f; }

    for (int s = 0; s < 16; s++) {
        const int y = s * 8 + y_loc;
        float rowp[16];
#pragma unroll
        for (int ci = 0; ci < 16; ci++) rowp[ci] = 0.f;
        for (int i = 0; i < 4; i++) {
            const int x = xg + i * 32;
            const int e = ((d * 128 + y) * 128 + x) * 16;
            const uint4* p2 = (const uint4*)(y2 + e);
            const uint4* p4 = (const uint4*)(y4 + e);
            float f2a[16], f4a[16];
            unpack16(p2[0], p2[1], f2a);
            unpack16(p4[0], p4[1], f4a);
            float* sb = &sbuf[(y_loc * 128 + x) * 16];
#pragma unroll
            for (int ci = 0; ci < 16; ci++) {
                float xb = fmaxf((f2a[ci] - sA[ci]) * sA[16 + ci] + prw[y * 16 + ci], 0.f);
                float v  = fmaxf((f4a[ci] - sA[32 + ci]) * sA[48 + ci] + xb, 0.f);
                rowp[ci] += v;
                sb[ci] = v;
            }
        }
#pragma unroll
        for (int ci = 0; ci < 16; ci++) {
            float rv = rowp[ci];
            rv += __shfl_down(rv, 1, 32);
            rv += __shfl_down(rv, 2, 32);
            rv += __shfl_down(rv, 4, 32);
            rv += __shfl_down(rv, 8, 32);
            rv += __shfl_down(rv, 16, 32);
            rowp[ci] = rv;
        }
        if (xg == 0) {
#pragma unroll
            for (int ci = 0; ci < 16; ci++) {
                int oi = (ci * 2 + 0) * 16384 + d * 128 + y;
                if (bf) ((u16*)out)[oi] = f2bf(rowp[ci]);
                else    ((float*)out)[oi] = rowp[ci];
            }
        }
        __syncthreads();
#pragma unroll
        for (int yl = 0; yl < 8; yl++) {
#pragma unroll
            for (int j = 0; j < 8; j++) {
                float v = sbuf[(yl * 128 + xB) * 16 + chalf * 8 + j];
                colr[j] += v;
                if (s < 8) colr0[j] += v;
            }
        }
        __syncthreads();
    }
#pragma unroll
    for (int j = 0; j < 8; j++) {
        int c = chalf * 8 + j;
        float v = (xB == 0) ? colr0[j] : colr[j];
        int oi = (c * 2 + 1) * 16384 + d * 128 + xB;
        if (bf) ((u16*)out)[oi] = f2bf(v);
        else    ((float*)out)[oi] = v;
    }
}

extern "C" void kernel_launch(void* const* d_in, const int* in_sizes, int n_in,
                              void* d_out, int out_size, void* d_ws, size_t ws_size,
                              hipStream_t stream)
{
    if (ws_size < WS_NEED) {
        sentinel_k<<<(out_size + 255) / 256, 256, 0, stream>>>((u16*)d_out, out_size);
        return;
    }
    const void* proj = d_in[0];
    const void* w1 = d_in[1]; const void* b1 = d_in[2];
    const void* w2 = d_in[3]; const void* b2 = d_in[4];
    const void* w3 = d_in[5]; const void* b3 = d_in[6];
    const void* w4 = d_in[7]; const void* b4 = d_in[8];

    u16* bufA = (u16*)d_ws;                    // y1, reused for y4
    u16* bufB = bufA + VOL_ELEMS;              // y2
    u16* bufC = bufB + VOL_ELEMS;              // y3
    float* st = (float*)(bufC + VOL_ELEMS);
    int* flag = (int*)(st + 256);

    init_k<<<1, 64, 0, stream>>>(w1, st, flag);

    dim3 cg(8, 16, 32), cb(256);
    conv_k<0><<<cg, cb, 0, stream>>>(nullptr, proj, nullptr, w1, b1, flag, bufA, st + 0);
    finalize_k<<<1, 64, 0, stream>>>(st + 0);
    conv_k<1><<<cg, cb, 0, stream>>>(bufA, nullptr, st + 0, w2, b2, flag, bufB, st + 64);
    finalize_k<<<1, 64, 0, stream>>>(st + 64);
    conv_k<2><<<cg, cb, 0, stream>>>(bufB, proj, st + 64, w3, b3, flag, bufC, st + 128);
    finalize_k<<<1, 64, 0, stream>>>(st + 128);
    conv_k<1><<<cg, cb, 0, stream>>>(bufC, nullptr, st + 128, w4, b4, flag, bufA, st + 192);
    finalize_k<<<1, 64, 0, stream>>>(st + 192);
    fproj_k<<<128, 256, 0, stream>>>(bufB, bufA, proj, st, flag, d_out);
}